// Round 13
// baseline (6849.699 us; speedup 1.0000x reference)
//
#include <hip/hip_runtime.h>

typedef unsigned short u16;
typedef __attribute__((ext_vector_type(8))) short short8;
typedef __attribute__((ext_vector_type(4))) float f32x4;

#define DEV __device__ __forceinline__

// B=192, T=64, ACT=16, EMB=1024, STOCH=32, DETER=600, HID=600
// out row stride 1392: [mean_po 0, std_po 32, stoch_po 64, deter 96,
//                       mean_pr 696, std_pr 728, stoch_pr 760, deter 792]
// xd row layout [192][1280]: [x 0..599 | 0 | deter 640..1239 | 0]  (2560 B/row)
#define XDS 1280
#define PN 1920   // parts row stride: 3840 B = 15 x 256 -> no cross-group lines
#define POLL_CAP 16384

DEV u16 f2bf(float f) {
  unsigned u = __float_as_uint(f);
  u = (u + 0x7FFFu + ((u >> 16) & 1u)) >> 16;
  return (u16)u;
}
DEV float bf2f(u16 h) { return __uint_as_float(((unsigned)h) << 16); }
DEV float sigf(float x) { return 1.f / (1.f + __expf(-x)); }
DEV float eluf(float x) { return x > 0.f ? x : __expf(x) - 1.f; }
DEV f32x4 MF(short8 a, short8 b, f32x4 c) {
  return __builtin_amdgcn_mfma_f32_16x16x32_bf16(a, b, c, 0, 0, 0);
}

// ---- data-path cache-scope helpers: LOC=true -> sc0 (bypass L1, served by
// ---- the XCD's L2; valid only when all communicating blocks share the XCD);
// ---- LOC=false -> sc0 sc1 (device scope via MALL; r9/r11-proven).
template <bool LOC> DEV void ld16d(short8& d, const u16* p) {
  if constexpr (LOC)
    asm volatile("global_load_dwordx4 %0, %1, off sc0" : "=v"(d) : "v"(p));
  else
    asm volatile("global_load_dwordx4 %0, %1, off sc0 sc1" : "=v"(d) : "v"(p));
}
DEV void vdrain() {
  asm volatile("s_waitcnt vmcnt(0)" ::: "memory");
  __builtin_amdgcn_sched_barrier(0);
}
template <bool LOC> DEV void st4d(void* p, unsigned v) {
  if constexpr (LOC)
    asm volatile("global_store_dword %0, %1, off sc0" ::"v"(p), "v"(v) : "memory");
  else
    asm volatile("global_store_dword %0, %1, off sc0 sc1" ::"v"(p), "v"(v) : "memory");
}
// ---- flags: ALWAYS device scope (MALL coherent, no dirty-L2 copies) ----
DEV unsigned fld(const unsigned* p) {
  return __hip_atomic_load(p, __ATOMIC_RELAXED, __HIP_MEMORY_SCOPE_AGENT);
}
DEV void fst(unsigned* p, unsigned v) {
  __hip_atomic_store(p, v, __ATOMIC_RELAXED, __HIP_MEMORY_SCOPE_AGENT);
}

// ---------------- f32 -> bf16 with zero row padding (k-major) ----------------
__global__ __launch_bounds__(256) void conv_pad(const float* __restrict__ src,
                                                u16* __restrict__ dst,
                                                int K, int N, int Kpad, int srcRowOff) {
  size_t total = (size_t)Kpad * N;
  for (size_t idx = (size_t)blockIdx.x * 256 + threadIdx.x; idx < total;
       idx += (size_t)gridDim.x * 256) {
    int k = (int)(idx / (size_t)N);
    int n = (int)(idx % (size_t)N);
    dst[idx] = (k < K) ? f2bf(src[(size_t)(k + srcRowOff) * N + n]) : (u16)0;
  }
}

// ---------------- f32 [K0][N0] -> bf16 transposed [Npad][Kpad] ----------------
__global__ __launch_bounds__(256) void conv_T(const float* __restrict__ src,
                                              u16* __restrict__ dst,
                                              int K0, int N0, int Kpad, int Npad) {
  size_t total = (size_t)Npad * Kpad;
  for (size_t idx = (size_t)blockIdx.x * 256 + threadIdx.x; idx < total;
       idx += (size_t)gridDim.x * 256) {
    int n = (int)(idx / (size_t)Kpad);
    int k = (int)(idx % (size_t)Kpad);
    dst[idx] = (k < K0 && n < N0) ? f2bf(src[(size_t)k * N0 + n]) : (u16)0;
  }
}

// gruw [1200][1800] -> bf16 [1824 n][1280 k2]; k2<600 -> x-row k2,
// 640<=k2<1240 -> deter-row k2-40, else zero; n>=1800 zero.
__global__ __launch_bounds__(256) void conv_gruT(const float* __restrict__ src,
                                                 u16* __restrict__ dst) {
  size_t total = 1824ull * 1280;
  for (size_t idx = (size_t)blockIdx.x * 256 + threadIdx.x; idx < total;
       idx += (size_t)gridDim.x * 256) {
    int n = (int)(idx / 1280);
    int k2 = (int)(idx % 1280);
    int ko = (k2 < 600) ? k2 : (k2 >= 640 && k2 < 1240) ? (k2 - 40) : -1;
    dst[idx] = (n < 1800 && ko >= 0) ? f2bf(src[(size_t)ko * 1800 + n]) : (u16)0;
  }
}

// ---------------- MFMA 64x64 tile core (setup/tail GEMMs) ----
DEV void mfma_tile(const u16 (*As)[72], const u16 (*Bs)[72], int wm, int wn,
                   int lane, f32x4 acc[2][2]) {
#pragma unroll
  for (int s = 0; s < 2; ++s) {
    const int ko = s * 32 + ((lane >> 4) << 3);
    short8 a0 = *reinterpret_cast<const short8*>(&As[wm + (lane & 15)][ko]);
    short8 a1 = *reinterpret_cast<const short8*>(&As[wm + 16 + (lane & 15)][ko]);
    short8 b0 = *reinterpret_cast<const short8*>(&Bs[wn + (lane & 15)][ko]);
    short8 b1 = *reinterpret_cast<const short8*>(&Bs[wn + 16 + (lane & 15)][ko]);
    acc[0][0] = MF(a0, b0, acc[0][0]);
    acc[0][1] = MF(a0, b1, acc[0][1]);
    acc[1][0] = MF(a1, b0, acc[1][0]);
    acc[1][1] = MF(a1, b1, acc[1][1]);
  }
}

// ---------------- generic 64x64-tiled bf16 GEMM (setup/tail) ----------------
// EPI: 2 = +bias, elu, bf16 out ; 4 = +bias, bf16 out, epre-permuted store
template <int EPI>
__global__ __launch_bounds__(256) void gemm64(
    const u16* __restrict__ A, int lda, const u16* __restrict__ W, int ldw,
    const float* __restrict__ bias, void* __restrict__ Cv, int ldc,
    int Nstore, int N, int K) {
  __shared__ u16 As[64][72];
  __shared__ u16 Bs[64][72];
  const int tid = threadIdx.x, lane = tid & 63, wave = tid >> 6;
  const int wm = (wave & 1) * 32, wn = (wave >> 1) * 32;
  const int bn0 = blockIdx.x * 64, bm0 = blockIdx.y * 64;
  const int am = tid >> 2, ak0 = (tid & 3) * 16;
  const int bk = tid >> 3, bn = (tid & 7) * 8;

  f32x4 acc[2][2] = {};
  for (int k0 = 0; k0 < K; k0 += 64) {
    __syncthreads();
    {
      const u16* src = A + (size_t)(bm0 + am) * lda + k0 + ak0;
      *reinterpret_cast<short8*>(&As[am][ak0]) = *reinterpret_cast<const short8*>(src);
      *reinterpret_cast<short8*>(&As[am][ak0 + 8]) = *reinterpret_cast<const short8*>(src + 8);
    }
    {
      int gn = bn0 + bn;
#pragma unroll
      for (int h = 0; h < 2; ++h) {
        int kk = k0 + bk + h * 32;
        short8 v;
        if (gn + 7 < N) {
          v = *reinterpret_cast<const short8*>(W + (size_t)kk * ldw + gn);
        } else {
          for (int j = 0; j < 8; ++j)
            v[j] = (gn + j < N) ? (short)W[(size_t)kk * ldw + gn + j] : (short)0;
        }
#pragma unroll
        for (int j = 0; j < 8; ++j) Bs[bn + j][bk + h * 32] = (u16)v[j];
      }
    }
    __syncthreads();
    mfma_tile(As, Bs, wm, wn, lane, acc);
  }

#pragma unroll
  for (int r = 0; r < 2; ++r)
#pragma unroll
    for (int c = 0; c < 2; ++c)
#pragma unroll
      for (int i = 0; i < 4; ++i) {
        int grow = bm0 + wm + r * 16 + ((lane >> 4) << 2) + i;
        int gcol = bn0 + wn + c * 16 + (lane & 15);
        if (gcol >= Nstore) continue;
        bool ok = gcol < N;
        float v = acc[r][c][i] + (ok ? bias[gcol] : 0.f);
        if (EPI == 2) {
          v = eluf(v);
          ((u16*)Cv)[(size_t)grow * ldc + gcol] = ok ? f2bf(v) : (u16)0;
        } else {  // EPI 4: epre[t][b][600] layout
          size_t row2 = (size_t)(grow & 63) * 192 + (size_t)(grow >> 6);
          ((u16*)Cv)[row2 * 600 + gcol] = f2bf(v);
        }
      }
}

// ------- init: x(t=0)=elu(action part), deter=0, pads=0, flags/xcc=0 --------
__global__ __launch_bounds__(256) void k_init(const float* __restrict__ action,
                                              const float* __restrict__ img1w,
                                              const float* __restrict__ img1b,
                                              u16* __restrict__ xd,
                                              unsigned* __restrict__ flags) {
  __shared__ float act[16];
  int b = blockIdx.x, tid = threadIdx.x;
  if (b == 0)
    for (int i = tid; i < 9280; i += 256) flags[i] = 0;  // 9216 flags + 64 xcc
  if (tid < 16) act[tid] = action[(size_t)b * 64 * 16 + tid];  // t = 0
  __syncthreads();
  for (int h = tid; h < 600; h += 256) {
    float s = img1b[h];
#pragma unroll
    for (int a = 0; a < 16; ++a) s += act[a] * img1w[(size_t)(32 + a) * 600 + h];
    xd[(size_t)b * XDS + h] = f2bf(eluf(s));
  }
  for (int j = tid; j < 680; j += 256) xd[(size_t)b * XDS + 600 + j] = 0;
}

// ---------------- batched prior head (tail; N=64 GEMM + dist outputs) --------
__global__ __launch_bounds__(256) void head_prior(
    const u16* __restrict__ A, const u16* __restrict__ W,
    const float* __restrict__ bias64, const float* __restrict__ noise,
    float* __restrict__ out) {
  __shared__ u16 As[64][72];
  __shared__ u16 Bs[64][72];
  __shared__ float sl[64][68];
  const int tid = threadIdx.x, lane = tid & 63, wave = tid >> 6;
  const int wm = (wave & 1) * 32, wn = (wave >> 1) * 32;
  const int bm0 = blockIdx.x * 64;
  const int am = tid >> 2, ak0 = (tid & 3) * 16;
  const int bk = tid >> 3, bn = (tid & 7) * 8;

  f32x4 acc[2][2] = {};
  for (int k0 = 0; k0 < 640; k0 += 64) {
    __syncthreads();
    {
      const u16* src = A + (size_t)(bm0 + am) * 640 + k0 + ak0;
      *reinterpret_cast<short8*>(&As[am][ak0]) = *reinterpret_cast<const short8*>(src);
      *reinterpret_cast<short8*>(&As[am][ak0 + 8]) = *reinterpret_cast<const short8*>(src + 8);
    }
#pragma unroll
    for (int h = 0; h < 2; ++h) {
      int kk = k0 + bk + h * 32;
      short8 v = *reinterpret_cast<const short8*>(W + (size_t)kk * 64 + bn);
#pragma unroll
      for (int j = 0; j < 8; ++j) Bs[bn + j][bk + h * 32] = (u16)v[j];
    }
    __syncthreads();
    mfma_tile(As, Bs, wm, wn, lane, acc);
  }
#pragma unroll
  for (int r = 0; r < 2; ++r)
#pragma unroll
    for (int c = 0; c < 2; ++c)
#pragma unroll
      for (int i = 0; i < 4; ++i) {
        int col = wn + c * 16 + (lane & 15);
        sl[wm + r * 16 + ((lane >> 4) << 2) + i][col] = acc[r][c][i] + bias64[col];
      }
  __syncthreads();
  for (int task = tid; task < 64 * 32; task += 256) {
    int r = task >> 5, j = task & 31;
    size_t orow = (size_t)(bm0 + r);
    size_t base = orow * 1392 + 696;
    float mean = sl[r][j];
    float sd = 2.f * sigf(0.5f * sl[r][32 + j]) + 0.1f;
    float st = mean + sd * noise[orow * 32 + j];
    out[base + j] = mean;
    out[base + 32 + j] = sd;
    out[base + 64 + j] = st;
  }
}

// ---- XCD-local scan: 8 groups (24 rows) x 6 peer-blocks. Group g = blocks
// ---- {g, g+8, ..., g+40} -> same XCD under round-robin; verified via XCC_ID,
// ---- else device-scope data fallback. Flags always device-scope, 256B/flag.
// ---- Each peer j: 4 rows (LN/obs/head/img1) + 304-col GRU GEMM slice.
struct ScanArgs {
  u16* xd;            // [192][1280] carry (group-line-disjoint: 2560 B rows)
  u16* parts;         // [192][PN] bf16 (3840 B rows)
  const u16* gruwT;   // [1824 n][1280 k] remapped (cached)
  const float* grub;
  const float* lns;
  const float* lnb;
  u16* dall;          // [12288][640] (nt; read by tail)
  float* out;
  const u16* o1wT;    // [608][608]
  const u16* epre;    // [64][192][600] (t-major, nt loads)
  const u16* o2wT;    // [64][608]
  const float* obs2b;
  const float* npo;
  const u16* w1pT;    // [640][64]
  const float* img1b;
  const float* action;
  unsigned* flags;    // 9216 dwords: flag (kind*6+j)*8+g at dword ((..))*64
  unsigned* xcc;      // 64 dwords
};

template <bool LOC>
DEV void scan_body(const ScanArgs& A, int g, int j,
                   u16 (*alD)[648], u16 (*alX)[648], u16 (*dlD)[648],
                   u16 (*hl)[616], u16 (*es)[608], u16 (*pl)[PN],
                   float (*dsh)[600], float (*sl)[68], u16 (*xa)[72]) {
  const int tid = threadIdx.x;
  const int lane = tid & 63, wave = tid >> 6;
  const int l15 = lane & 15;
  const int koff = (lane >> 4) << 3;
  const int crow = (lane >> 4) << 2;
  const int R0 = g * 24;
  const int Rm0 = R0 + j * 4;
  unsigned* F = A.flags;

  auto flagp = [&](int kind, int jj) -> unsigned* {
    return F + (size_t)((kind * 6 + jj) * 8 + g) * 64;
  };
  auto waitpeers = [&](int kind, unsigned tgt) {
    __syncthreads();
    if (wave == 0) {
      int it = 0;
      for (;;) {
        unsigned v = (lane < 6) ? fld(flagp(kind, lane)) : tgt;
        if (__all((int)(v >= tgt))) break;
        if (++it > POLL_CAP) break;  // fail-visible, never hang
        __builtin_amdgcn_s_sleep(2);
      }
    }
    __syncthreads();
  };

  const int qn = (26 - wave) / 8;  // tasks per wave: waves 0-2: 3, 3-7: 2
  const u16* bq[3];
  int cq[3];
#pragma unroll
  for (int s2 = 0; s2 < 3; ++s2) {
    int q = wave + 8 * s2;
    bq[s2] = A.gruwT + (size_t)((j * 19 + (q < 19 ? q : 0)) * 16 + l15) * 1280 + koff;
    cq[s2] = (j * 19 + q) * 16 + l15;
  }

  for (int t = 0; t < 64; ++t) {
    f32x4 acc[3][2] = {};
    // ======== GEMM deter half (K 640..1279) ========
    waitpeers(1, (unsigned)t);
    {
      short8 tmp[4];
#pragma unroll
      for (int s2 = 0; s2 < 4; ++s2) {
        int i2 = tid + 512 * s2;
        if (i2 < 1920) {
          int r = i2 / 80, o = (i2 - r * 80) * 8;
          ld16d<LOC>(tmp[s2], A.xd + (size_t)(R0 + r) * XDS + 640 + o);
        }
      }
      vdrain();
#pragma unroll
      for (int s2 = 0; s2 < 4; ++s2) {
        int i2 = tid + 512 * s2;
        if (i2 < 1920) {
          int r = i2 / 80, o = (i2 - r * 80) * 8;
          *reinterpret_cast<short8*>(&alD[r][o]) = tmp[s2];
        }
      }
    }
    __syncthreads();
    for (int kk = 0; kk < 640; kk += 32) {
      short8 a0 = *reinterpret_cast<const short8*>(&alD[l15][koff + kk]);
      short8 a1 = *reinterpret_cast<const short8*>(&alD[16 + l15][koff + kk]);
#pragma unroll
      for (int s2 = 0; s2 < 3; ++s2)
        if (s2 < qn) {
          short8 b = *reinterpret_cast<const short8*>(bq[s2] + 640 + kk);
          acc[s2][0] = MF(a0, b, acc[s2][0]);
          acc[s2][1] = MF(a1, b, acc[s2][1]);
        }
    }
    // ======== GEMM x half (K 0..639) ========
    waitpeers(2, (unsigned)t);
    {
      short8 tmp[4];
#pragma unroll
      for (int s2 = 0; s2 < 4; ++s2) {
        int i2 = tid + 512 * s2;
        if (i2 < 1920) {
          int r = i2 / 80, o = (i2 - r * 80) * 8;
          ld16d<LOC>(tmp[s2], A.xd + (size_t)(R0 + r) * XDS + o);
        }
      }
      vdrain();
#pragma unroll
      for (int s2 = 0; s2 < 4; ++s2) {
        int i2 = tid + 512 * s2;
        if (i2 < 1920) {
          int r = i2 / 80, o = (i2 - r * 80) * 8;
          *reinterpret_cast<short8*>(&alX[r][o]) = tmp[s2];
        }
      }
    }
    __syncthreads();
    for (int kk = 0; kk < 640; kk += 32) {
      short8 a0 = *reinterpret_cast<const short8*>(&alX[l15][koff + kk]);
      short8 a1 = *reinterpret_cast<const short8*>(&alX[16 + l15][koff + kk]);
#pragma unroll
      for (int s2 = 0; s2 < 3; ++s2)
        if (s2 < qn) {
          short8 b = *reinterpret_cast<const short8*>(bq[s2] + kk);
          acc[s2][0] = MF(a0, b, acc[s2][0]);
          acc[s2][1] = MF(a1, b, acc[s2][1]);
        }
    }
    // ======== store parts slice ========
#pragma unroll
    for (int s2 = 0; s2 < 3; ++s2)
      if (s2 < qn) {
        int c = cq[s2];
#pragma unroll
        for (int mt = 0; mt < 2; ++mt)
#pragma unroll
          for (int i = 0; i < 4; ++i) {
            int row = mt * 16 + crow + i;
            unsigned hv = f2bf(acc[s2][mt][i]);
            unsigned ov = (unsigned)__shfl_xor((int)hv, 1);
            if (!(lane & 1) && row < 24 && c < 1800)
              st4d<LOC>(A.parts + (size_t)(R0 + row) * PN + c, hv | (ov << 16));
          }
      }
    vdrain();
    __syncthreads();
    if (tid == 0) fst(flagp(0, j), (unsigned)(t + 1));

    // ======== LN + gates + deter (own 4 rows) ========
    waitpeers(0, (unsigned)(t + 1));
    {
      short8 tmp[2];
#pragma unroll
      for (int s2 = 0; s2 < 2; ++s2) {
        int i2 = tid + 512 * s2;
        if (i2 < 900) {
          int r = i2 / 225, o = (i2 - r * 225) * 8;
          ld16d<LOC>(tmp[s2], A.parts + (size_t)(Rm0 + r) * PN + o);
        }
      }
      vdrain();
#pragma unroll
      for (int s2 = 0; s2 < 2; ++s2) {
        int i2 = tid + 512 * s2;
        if (i2 < 900) {
          int r = i2 / 225, o = (i2 - r * 225) * 8;
          *reinterpret_cast<short8*>(&pl[r][o]) = tmp[s2];
        }
      }
    }
    __syncthreads();
    if (wave < 4) {
      const int rr = wave;
      const int Rm = Rm0 + rr;
      float s = 0.f;
      for (int j2 = lane; j2 < 1800; j2 += 64) s += bf2f(pl[rr][j2]) + A.grub[j2];
#pragma unroll
      for (int o = 32; o; o >>= 1) s += __shfl_xor(s, o);
      float m = s * (1.f / 1800.f);
      float q2 = 0.f;
      for (int j2 = lane; j2 < 1800; j2 += 64) {
        float d = bf2f(pl[rr][j2]) + A.grub[j2] - m;
        q2 += d * d;
      }
#pragma unroll
      for (int o = 32; o; o >>= 1) q2 += __shfl_xor(q2, o);
      float rstd = rsqrtf(q2 * (1.f / 1800.f) + 1e-5f);
      size_t orow = (size_t)Rm * 64 + t;
      for (int j2 = lane; j2 < 600; j2 += 64) {
        float p0 = (bf2f(pl[rr][j2]) + A.grub[j2] - m) * rstd * A.lns[j2] + A.lnb[j2];
        float p1 = (bf2f(pl[rr][600 + j2]) + A.grub[600 + j2] - m) * rstd *
                       A.lns[600 + j2] + A.lnb[600 + j2];
        float p2 = (bf2f(pl[rr][1200 + j2]) + A.grub[1200 + j2] - m) * rstd *
                       A.lns[1200 + j2] + A.lnb[1200 + j2];
        float r2 = sigf(p0);
        float cd = tanhf(r2 * p1);
        float u = sigf(p2 - 1.f);
        float dn = u * cd + (1.f - u) * dsh[rr][j2];
        dsh[rr][j2] = dn;
        dlD[rr][j2] = f2bf(dn);
        float* ob = A.out + orow * 1392;
        __builtin_nontemporal_store(dn, ob + 96 + j2);
        __builtin_nontemporal_store(dn, ob + 792 + j2);
        unsigned hv = f2bf(dn);
        unsigned ov = (unsigned)__shfl_xor((int)hv, 1);
        if (!(lane & 1)) {
          st4d<LOC>(A.xd + (size_t)Rm * XDS + 640 + j2, hv | (ov << 16));
          __builtin_nontemporal_store(hv | (ov << 16),
                                      (unsigned*)(A.dall + orow * 640 + j2));
        }
      }
      if (lane < 20)
        __builtin_nontemporal_store(0u,
                                    (unsigned*)(A.dall + orow * 640 + 600 + 2 * lane));
      vdrain();
    } else {
      const int t2 = tid - 256;
#pragma unroll
      for (int s2 = 0; s2 < 2; ++s2) {
        int i2 = t2 + 256 * s2;
        if (i2 < 300) {
          int r = i2 / 75, o = (i2 - r * 75) * 8;
          short8 ev = __builtin_nontemporal_load(
              (const short8*)(A.epre + ((size_t)t * 192 + Rm0 + r) * 600 + o));
          *reinterpret_cast<short8*>(&es[r][o]) = ev;
        }
      }
    }
    __syncthreads();
    if (tid == 0) fst(flagp(1, j), (unsigned)(t + 1));

    // ======== obs1: h = elu(deter @ o1w + epre) ========
#pragma unroll
    for (int s2 = 0; s2 < 5; ++s2) {
      int g2 = wave + 8 * s2;
      if (g2 < 38) {
        const u16* bp = A.o1wT + (size_t)(g2 * 16 + l15) * 608 + koff;
        f32x4 ac{};
        for (int kk = 0; kk < 608; kk += 32)
          ac = MF(*reinterpret_cast<const short8*>(&dlD[l15][koff + kk]),
                  *reinterpret_cast<const short8*>(bp + kk), ac);
        int cw = g2 * 16 + l15;
        if (crow == 0 && cw < 600) {
#pragma unroll
          for (int i = 0; i < 4; ++i)
            hl[i][cw] = f2bf(eluf(ac[i] + bf2f(es[i][cw])));
        }
      }
    }
    __syncthreads();
    // ======== obs2 ========
    if (wave < 4) {
      const int n0 = wave * 16;
      const u16* bp = A.o2wT + (size_t)(n0 + l15) * 608 + koff;
      f32x4 ac{};
      for (int kk = 0; kk < 608; kk += 32)
        ac = MF(*reinterpret_cast<const short8*>(&hl[l15][koff + kk]),
                *reinterpret_cast<const short8*>(bp + kk), ac);
      if (crow == 0) {
#pragma unroll
        for (int i = 0; i < 4; ++i) sl[i][n0 + l15] = ac[i] + A.obs2b[n0 + l15];
      }
    }
    __syncthreads();
    // ======== head + stoch + xa ========
    if (tid < 128) {
      int r = tid >> 5, j2 = tid & 31;
      size_t orow = (size_t)(Rm0 + r) * 64 + t;
      float mean = sl[r][j2];
      float sd = 2.f * sigf(0.5f * sl[r][32 + j2]) + 0.1f;
      float st =
          mean + sd * __builtin_nontemporal_load((const float*)&A.npo[orow * 32 + j2]);
      float* ob = A.out + orow * 1392;
      __builtin_nontemporal_store(mean, ob + j2);
      __builtin_nontemporal_store(sd, ob + 32 + j2);
      __builtin_nontemporal_store(st, ob + 64 + j2);
      xa[r][j2] = f2bf(st);
    } else if (tid < 192) {
      int r = (tid - 128) >> 4, a2 = tid & 15;
      float av = (t < 63)
                     ? __builtin_nontemporal_load(
                           (const float*)&A.action[((size_t)(Rm0 + r) * 64 + t + 1) * 16 + a2])
                     : 0.f;
      xa[r][32 + a2] = f2bf(av);
    }
    __syncthreads();
    // ======== img1 -> x(t+1) ========
    if (t < 63) {
#pragma unroll
      for (int s2 = 0; s2 < 5; ++s2) {
        int g2 = wave + 8 * s2;
        if (g2 < 38) {
          const u16* bp = A.w1pT + (size_t)(g2 * 16 + l15) * 64 + koff;
          f32x4 ax{};
          ax = MF(*reinterpret_cast<const short8*>(&xa[l15][koff]),
                  *reinterpret_cast<const short8*>(bp), ax);
          ax = MF(*reinterpret_cast<const short8*>(&xa[l15][32 + koff]),
                  *reinterpret_cast<const short8*>(bp + 32), ax);
          int cx = g2 * 16 + l15;
          float bi = (cx < 600) ? A.img1b[cx] : 0.f;
          if (crow == 0) {
#pragma unroll
            for (int i = 0; i < 4; ++i) {
              unsigned hv = f2bf(eluf(ax[i] + bi));
              unsigned ov = (unsigned)__shfl_xor((int)hv, 1);
              if (!(lane & 1) && cx < 600)
                st4d<LOC>(A.xd + (size_t)(Rm0 + i) * XDS + cx, hv | (ov << 16));
            }
          }
        }
      }
      vdrain();
      __syncthreads();
      if (tid == 0) fst(flagp(2, j), (unsigned)(t + 1));
    }
  }
}

__global__ __launch_bounds__(512, 1) void scan64(ScanArgs A) {
  __shared__ u16 alD[32][648];
  __shared__ u16 alX[32][648];
  __shared__ u16 dlD[16][648];
  __shared__ u16 hl[16][616];
  __shared__ u16 es[4][608];
  __shared__ u16 pl[4][PN];
  __shared__ float dsh[4][600];
  __shared__ float sl[4][68];
  __shared__ u16 xa[16][72];
  __shared__ int okSh;

  const int tid = threadIdx.x;
  const int bid = blockIdx.x;
  const int g = bid & 7, j = bid >> 3;

  // XCD coherence-domain detection (sc0 data path only if all peers same XCC)
  unsigned xcc;
  asm volatile("s_getreg_b32 %0, hwreg(HW_REG_XCC_ID)" : "=s"(xcc));
  if (tid == 0)
    __hip_atomic_store(&A.xcc[bid], xcc + 1u, __ATOMIC_RELAXED,
                       __HIP_MEMORY_SCOPE_AGENT);
  if (tid < 64) {
    unsigned v = 1u;
    int it = 0;
    for (;;) {
      v = (tid < 6) ? __hip_atomic_load(&A.xcc[tid * 8 + g], __ATOMIC_RELAXED,
                                        __HIP_MEMORY_SCOPE_AGENT)
                    : 1u;
      if (__all((int)(v != 0u))) break;
      if (++it > POLL_CAP) break;  // fail-visible, never hang
      __builtin_amdgcn_s_sleep(1);
    }
    unsigned ref = (unsigned)__shfl((int)v, 0);
    int same = __all((int)((tid < 6) ? (v == ref && v != 0u) : 1));
    if (tid == 0) okSh = same;
  }
  // zero-init LDS (pad rows/cols that MFMA reads but phases never write)
  for (int i = tid; i < 8 * 648; i += 512) {
    alD[24 + i / 648][i % 648] = 0;
    alX[24 + i / 648][i % 648] = 0;
  }
  for (int i = tid; i < 16 * 648; i += 512) dlD[i / 648][i % 648] = 0;
  for (int i = tid; i < 16 * 616; i += 512) hl[i / 616][i % 616] = 0;
  for (int i = tid; i < 16 * 72; i += 512) xa[i / 72][i % 72] = 0;
  for (int i = tid; i < 4 * 600; i += 512) dsh[i / 600][i % 600] = 0.f;
  __syncthreads();
  if (okSh)
    scan_body<true>(A, g, j, alD, alX, dlD, hl, es, pl, dsh, sl, xa);
  else
    scan_body<false>(A, g, j, alD, alX, dlD, hl, es, pl, dsh, sl, xa);
}

// ---------------- launch ----------------
extern "C" void kernel_launch(void* const* d_in, const int* in_sizes, int n_in,
                              void* d_out, int out_size, void* d_ws, size_t ws_size,
                              hipStream_t stream) {
  (void)in_sizes; (void)n_in; (void)out_size; (void)ws_size;
  const float* action = (const float*)d_in[0];
  const float* embed = (const float*)d_in[1];
  const float* npr = (const float*)d_in[2];
  const float* npo = (const float*)d_in[3];
  const float* img1w = (const float*)d_in[4];
  const float* img1b = (const float*)d_in[5];
  const float* gruw = (const float*)d_in[6];
  const float* grub = (const float*)d_in[7];
  const float* lns = (const float*)d_in[8];
  const float* lnb = (const float*)d_in[9];
  const float* img2w = (const float*)d_in[10];
  const float* img2b = (const float*)d_in[11];
  const float* img3w = (const float*)d_in[12];
  const float* img3b = (const float*)d_in[13];
  const float* obs1w = (const float*)d_in[14];
  const float* obs1b = (const float*)d_in[15];
  const float* obs2w = (const float*)d_in[16];
  const float* obs2b = (const float*)d_in[17];
  float* out = (float*)d_out;
  char* ws = (char*)d_ws;

  size_t off = 0;
  auto alloc = [&](size_t bytes) {
    size_t o = off;
    off += (bytes + 255) & ~(size_t)255;
    return o;
  };
  size_t o_flags = alloc(9280 * 4);
  size_t o_embed = alloc(12288ull * 1024 * 2);  // reused as dall (12288x640)
  size_t o_epre = alloc(12288ull * 600 * 2);    // reused (with o_wemb) as h_img
  size_t o_wemb = alloc(1024ull * 600 * 2);
  size_t o_gruwT = alloc(1824ull * 1280 * 2);
  size_t o_o1wT = alloc(608ull * 608 * 2);
  size_t o_o2wT = alloc(64ull * 608 * 2);
  size_t o_w1pT = alloc(640ull * 64 * 2);
  size_t o_i2w = alloc(640ull * 600 * 2);
  size_t o_i3w = alloc(640ull * 64 * 2);
  size_t o_xd = alloc(192ull * XDS * 2);
  size_t o_parts = alloc(192ull * PN * 2);

  unsigned* flags = (unsigned*)(ws + o_flags);
  u16* embed_bf = (u16*)(ws + o_embed);
  u16* dall = (u16*)(ws + o_embed);
  u16* epre = (u16*)(ws + o_epre);
  u16* himg = (u16*)(ws + o_epre);
  u16* wemb = (u16*)(ws + o_wemb);
  u16* gruwT = (u16*)(ws + o_gruwT);
  u16* o1wT = (u16*)(ws + o_o1wT);
  u16* o2wT = (u16*)(ws + o_o2wT);
  u16* w1pT = (u16*)(ws + o_w1pT);
  u16* i2wb = (u16*)(ws + o_i2w);
  u16* i3wb = (u16*)(ws + o_i3w);
  u16* xd = (u16*)(ws + o_xd);
  u16* parts = (u16*)(ws + o_parts);

  auto cgr = [](size_t total) {
    size_t g = (total + 255) / 256;
    return (unsigned)(g > 4096 ? 4096 : g);
  };

  // setup conversions
  conv_pad<<<cgr(12288ull * 1024), 256, 0, stream>>>(embed, embed_bf, 12288, 1024, 12288, 0);
  conv_pad<<<cgr(1024ull * 600), 256, 0, stream>>>(obs1w, wemb, 1024, 600, 1024, 600);
  conv_pad<<<cgr(640ull * 600), 256, 0, stream>>>(img2w, i2wb, 600, 600, 640, 0);
  conv_pad<<<cgr(640ull * 64), 256, 0, stream>>>(img3w, i3wb, 600, 64, 640, 0);
  conv_gruT<<<cgr(1824ull * 1280), 256, 0, stream>>>(gruw, gruwT);
  conv_T<<<cgr(608ull * 608), 256, 0, stream>>>(obs1w, o1wT, 600, 600, 608, 608);
  conv_T<<<cgr(64ull * 608), 256, 0, stream>>>(obs2w, o2wT, 600, 64, 608, 64);
  conv_T<<<cgr(640ull * 64), 256, 0, stream>>>(img1w, w1pT, 48, 600, 64, 640);

  k_init<<<192, 256, 0, stream>>>(action, img1w, img1b, xd, flags);

  // epre[t][b][600] = embed @ obs1_w[600:,:] + obs1_b   (bf16, t-major)
  gemm64<4><<<dim3(10, 192), 256, 0, stream>>>(embed_bf, 1024, wemb, 600, obs1b,
                                               epre, 600, 600, 600, 1024);

  // XCD-local scan: 48 blocks = 8 groups x 6 peers
  ScanArgs sa;
  sa.xd = xd; sa.parts = parts;
  sa.gruwT = gruwT; sa.grub = grub; sa.lns = lns; sa.lnb = lnb;
  sa.dall = dall; sa.out = out;
  sa.o1wT = o1wT; sa.epre = epre;
  sa.o2wT = o2wT; sa.obs2b = obs2b; sa.npo = npo;
  sa.w1pT = w1pT; sa.img1b = img1b; sa.action = action;
  sa.flags = flags; sa.xcc = flags + 9216;
  scan64<<<48, 512, 0, stream>>>(sa);

  // batched prior: h_img = elu(deter_all @ img2_w + img2_b), then img3 head
  gemm64<2><<<dim3(10, 192), 256, 0, stream>>>(dall, 640, i2wb, 600, img2b,
                                               himg, 640, 640, 600, 640);
  head_prior<<<192, 256, 0, stream>>>(himg, i3wb, img3b, npr, out);
}

// Round 14
// 3645.263 us; speedup vs baseline: 1.8791x; 1.8791x over previous
//
#include <hip/hip_runtime.h>

typedef unsigned short u16;
typedef __attribute__((ext_vector_type(8))) short short8;
typedef __attribute__((ext_vector_type(4))) float f32x4;

#define DEV __device__ __forceinline__

// B=192, T=64, ACT=16, EMB=1024, STOCH=32, DETER=600, HID=600
// out row stride 1392: [mean_po 0, std_po 32, stoch_po 64, deter 96,
//                       mean_pr 696, std_pr 728, stoch_pr 760, deter 792]
// xd row [192][1280]: [x 0..599 | deter 600..1199 | pad 1200..1279]
#define XDS 1280
#define PN 1808        // parts bf16 row stride
#define POLL_CAP 65536

DEV u16 f2bf(float f) {
  unsigned u = __float_as_uint(f);
  u = (u + 0x7FFFu + ((u >> 16) & 1u)) >> 16;
  return (u16)u;
}
DEV float bf2f(u16 h) { return __uint_as_float(((unsigned)h) << 16); }
DEV float sigf(float x) { return 1.f / (1.f + __expf(-x)); }
DEV float eluf(float x) { return x > 0.f ? x : __expf(x) - 1.f; }
DEV f32x4 MF(short8 a, short8 b, f32x4 c) {
  return __builtin_amdgcn_mfma_f32_16x16x32_bf16(a, b, c, 0, 0, 0);
}

// ---- device-scope (MALL-coherent) helpers — r5..r9 replay-validated ----
DEV unsigned long long ald64(const void* p) {
  return __hip_atomic_load((const unsigned long long*)p, __ATOMIC_RELAXED,
                           __HIP_MEMORY_SCOPE_AGENT);
}
DEV short8 ald16B(const u16* p) {
  union { unsigned long long u[2]; short8 v; } x;
  x.u[0] = ald64(p);
  x.u[1] = ald64(p + 4);
  return x.v;
}
DEV void ast32(void* p, unsigned v) {
  __hip_atomic_store((unsigned*)p, v, __ATOMIC_RELAXED, __HIP_MEMORY_SCOPE_AGENT);
}
DEV unsigned fld(const unsigned* p) {
  return __hip_atomic_load(p, __ATOMIC_RELAXED, __HIP_MEMORY_SCOPE_AGENT);
}
DEV void fst(unsigned* p, unsigned v) {
  __hip_atomic_store(p, v, __ATOMIC_RELAXED, __HIP_MEMORY_SCOPE_AGENT);
}

// ---------------- f32 -> bf16 with zero row padding (k-major) ----------------
__global__ __launch_bounds__(256) void conv_pad(const float* __restrict__ src,
                                                u16* __restrict__ dst,
                                                int K, int N, int Kpad, int srcRowOff) {
  size_t total = (size_t)Kpad * N;
  for (size_t idx = (size_t)blockIdx.x * 256 + threadIdx.x; idx < total;
       idx += (size_t)gridDim.x * 256) {
    int k = (int)(idx / (size_t)N);
    int n = (int)(idx % (size_t)N);
    dst[idx] = (k < K) ? f2bf(src[(size_t)(k + srcRowOff) * N + n]) : (u16)0;
  }
}

// ---------------- f32 [K0][N0] -> bf16 transposed [Npad][Kpad] ----------------
__global__ __launch_bounds__(256) void conv_T(const float* __restrict__ src,
                                              u16* __restrict__ dst,
                                              int K0, int N0, int Kpad, int Npad) {
  size_t total = (size_t)Npad * Kpad;
  for (size_t idx = (size_t)blockIdx.x * 256 + threadIdx.x; idx < total;
       idx += (size_t)gridDim.x * 256) {
    int n = (int)(idx / (size_t)Kpad);
    int k = (int)(idx % (size_t)Kpad);
    dst[idx] = (k < K0 && n < N0) ? f2bf(src[(size_t)k * N0 + n]) : (u16)0;
  }
}

// ---------------- MFMA 64x64 tile core (setup/tail GEMMs) ----
DEV void mfma_tile(const u16 (*As)[72], const u16 (*Bs)[72], int wm, int wn,
                   int lane, f32x4 acc[2][2]) {
#pragma unroll
  for (int s = 0; s < 2; ++s) {
    const int ko = s * 32 + ((lane >> 4) << 3);
    short8 a0 = *reinterpret_cast<const short8*>(&As[wm + (lane & 15)][ko]);
    short8 a1 = *reinterpret_cast<const short8*>(&As[wm + 16 + (lane & 15)][ko]);
    short8 b0 = *reinterpret_cast<const short8*>(&Bs[wn + (lane & 15)][ko]);
    short8 b1 = *reinterpret_cast<const short8*>(&Bs[wn + 16 + (lane & 15)][ko]);
    acc[0][0] = MF(a0, b0, acc[0][0]);
    acc[0][1] = MF(a0, b1, acc[0][1]);
    acc[1][0] = MF(a1, b0, acc[1][0]);
    acc[1][1] = MF(a1, b1, acc[1][1]);
  }
}

// ---------------- generic 64x64-tiled bf16 GEMM (setup/tail) ----------------
// EPI: 2 = +bias, elu, bf16 out ; 4 = +bias, bf16 out, epre-permuted store
template <int EPI>
__global__ __launch_bounds__(256) void gemm64(
    const u16* __restrict__ A, int lda, const u16* __restrict__ W, int ldw,
    const float* __restrict__ bias, void* __restrict__ Cv, int ldc,
    int Nstore, int N, int K) {
  __shared__ u16 As[64][72];
  __shared__ u16 Bs[64][72];
  const int tid = threadIdx.x, lane = tid & 63, wave = tid >> 6;
  const int wm = (wave & 1) * 32, wn = (wave >> 1) * 32;
  const int bn0 = blockIdx.x * 64, bm0 = blockIdx.y * 64;
  const int am = tid >> 2, ak0 = (tid & 3) * 16;
  const int bk = tid >> 3, bn = (tid & 7) * 8;

  f32x4 acc[2][2] = {};
  for (int k0 = 0; k0 < K; k0 += 64) {
    __syncthreads();
    {
      const u16* src = A + (size_t)(bm0 + am) * lda + k0 + ak0;
      *reinterpret_cast<short8*>(&As[am][ak0]) = *reinterpret_cast<const short8*>(src);
      *reinterpret_cast<short8*>(&As[am][ak0 + 8]) = *reinterpret_cast<const short8*>(src + 8);
    }
    {
      int gn = bn0 + bn;
#pragma unroll
      for (int h = 0; h < 2; ++h) {
        int kk = k0 + bk + h * 32;
        short8 v;
        if (gn + 7 < N) {
          v = *reinterpret_cast<const short8*>(W + (size_t)kk * ldw + gn);
        } else {
          for (int j = 0; j < 8; ++j)
            v[j] = (gn + j < N) ? (short)W[(size_t)kk * ldw + gn + j] : (short)0;
        }
#pragma unroll
        for (int j = 0; j < 8; ++j) Bs[bn + j][bk + h * 32] = (u16)v[j];
      }
    }
    __syncthreads();
    mfma_tile(As, Bs, wm, wn, lane, acc);
  }

#pragma unroll
  for (int r = 0; r < 2; ++r)
#pragma unroll
    for (int c = 0; c < 2; ++c)
#pragma unroll
      for (int i = 0; i < 4; ++i) {
        int grow = bm0 + wm + r * 16 + ((lane >> 4) << 2) + i;
        int gcol = bn0 + wn + c * 16 + (lane & 15);
        if (gcol >= Nstore) continue;
        bool ok = gcol < N;
        float v = acc[r][c][i] + (ok ? bias[gcol] : 0.f);
        if (EPI == 2) {
          v = eluf(v);
          ((u16*)Cv)[(size_t)grow * ldc + gcol] = ok ? f2bf(v) : (u16)0;
        } else {  // EPI 4: epre[t][b][600] layout
          size_t row2 = (size_t)(grow & 63) * 192 + (size_t)(grow >> 6);
          ((u16*)Cv)[row2 * 600 + gcol] = f2bf(v);
        }
      }
}

// ------- init: x(t=0)=elu(action part), deter=0, pads=0, flags=0 ----------
__global__ __launch_bounds__(256) void k_init(const float* __restrict__ action,
                                              const float* __restrict__ img1w,
                                              const float* __restrict__ img1b,
                                              u16* __restrict__ xd,
                                              unsigned* __restrict__ flags) {
  __shared__ float act[16];
  int b = blockIdx.x, tid = threadIdx.x;
  if (b == 0)
    for (int i = tid; i < 6912; i += 256) flags[i] = 0;
  if (tid < 16) act[tid] = action[(size_t)b * 64 * 16 + tid];  // t = 0
  __syncthreads();
  for (int h = tid; h < 600; h += 256) {
    float s = img1b[h];
#pragma unroll
    for (int a = 0; a < 16; ++a) s += act[a] * img1w[(size_t)(32 + a) * 600 + h];
    xd[(size_t)b * XDS + h] = f2bf(eluf(s));
  }
  for (int j = tid; j < 680; j += 256) xd[(size_t)b * XDS + 600 + j] = 0;
}

// ---------------- batched prior head (tail; N=64 GEMM + dist outputs) --------
__global__ __launch_bounds__(256) void head_prior(
    const u16* __restrict__ A, const u16* __restrict__ W,
    const float* __restrict__ bias64, const float* __restrict__ noise,
    float* __restrict__ out) {
  __shared__ u16 As[64][72];
  __shared__ u16 Bs[64][72];
  __shared__ float sl[64][68];
  const int tid = threadIdx.x, lane = tid & 63, wave = tid >> 6;
  const int wm = (wave & 1) * 32, wn = (wave >> 1) * 32;
  const int bm0 = blockIdx.x * 64;
  const int am = tid >> 2, ak0 = (tid & 3) * 16;
  const int bk = tid >> 3, bn = (tid & 7) * 8;

  f32x4 acc[2][2] = {};
  for (int k0 = 0; k0 < 640; k0 += 64) {
    __syncthreads();
    {
      const u16* src = A + (size_t)(bm0 + am) * 640 + k0 + ak0;
      *reinterpret_cast<short8*>(&As[am][ak0]) = *reinterpret_cast<const short8*>(src);
      *reinterpret_cast<short8*>(&As[am][ak0 + 8]) = *reinterpret_cast<const short8*>(src + 8);
    }
#pragma unroll
    for (int h = 0; h < 2; ++h) {
      int kk = k0 + bk + h * 32;
      short8 v = *reinterpret_cast<const short8*>(W + (size_t)kk * 64 + bn);
#pragma unroll
      for (int j = 0; j < 8; ++j) Bs[bn + j][bk + h * 32] = (u16)v[j];
    }
    __syncthreads();
    mfma_tile(As, Bs, wm, wn, lane, acc);
  }
#pragma unroll
  for (int r = 0; r < 2; ++r)
#pragma unroll
    for (int c = 0; c < 2; ++c)
#pragma unroll
      for (int i = 0; i < 4; ++i) {
        int col = wn + c * 16 + (lane & 15);
        sl[wm + r * 16 + ((lane >> 4) << 2) + i][col] = acc[r][c][i] + bias64[col];
      }
  __syncthreads();
  for (int task = tid; task < 64 * 32; task += 256) {
    int r = task >> 5, j = task & 31;
    size_t orow = (size_t)(bm0 + r);
    size_t base = orow * 1392 + 696;
    float mean = sl[r][j];
    float sd = 2.f * sigf(0.5f * sl[r][32 + j]) + 0.1f;
    float st = mean + sd * noise[orow * 32 + j];
    out[base + j] = mean;
    out[base + 32 + j] = sd;
    out[base + 64 + j] = st;
  }
}

// ---- scan: 6 pipelines of {8 XCD-pinned A-blocks -> 2 BD-blocks} (r9 base) --
// A-block (h,x): rows h*32..+31, col-groups g == x (mod 8); split-K: deter half
// after deterF, x half after xF. BD-block b: LN+gates+deter, obs1, obs2, head,
// img1 for rows b*16..+15. Flags: A at idx 0..47, xF at 64+b, dF at 96+b
// (each flag 256B apart, device-scope).
struct ScanArgs {
  u16* xd;            // [192][1280] carry
  u16* parts;         // [192][PN] bf16 (bias fused)
  const u16* gruwT;   // [1808][1216] (cached, L2-resident per XCD slice)
  const float* grub;
  const float* lns;
  const float* lnb;
  u16* dall;          // [12288][640] (nt; read by tail)
  float* out;
  const u16* o1wT;    // [608][608]
  const u16* epre;    // [64][192][600] (t-major, nt loads)
  const u16* o2wT;    // [64][608]
  const float* obs2b;
  const float* npo;
  const u16* w1pT;    // [640][64]
  const float* img1b;
  const float* action;
  unsigned* flags;
};

__global__ __launch_bounds__(512, 1) void scan64(ScanArgs A) {
  const int bid = blockIdx.x, tid = threadIdx.x;
  const int lane = tid & 63, wave = tid >> 6;
  const int l15 = lane & 15;
  const int koff = (lane >> 4) << 3;   // k-octet offset within 32-k slab
  const int crow = (lane >> 4) << 2;   // C-row base within 16
  __shared__ __align__(16) char smem[143360];
  unsigned* F = A.flags;

  auto FA = [&](int idx) { return F + (size_t)idx * 64; };
  auto FX = [&](int b2) { return F + (size_t)(64 + b2) * 64; };
  auto FD = [&](int b2) { return F + (size_t)(96 + b2) * 64; };

  if (bid < 48) {
    // ================= A block: h = 32-row half, x = XCD col-comb ==========
    u16 (*stg)[1224] = (u16(*)[1224])smem;  // 32 x 1224 = 78,336 B
    const int h = bid >> 3, x = bid & 7;
    const int r0 = h * 32;
    const int fl = h * 8 + x;
    const int J = (x == 0) ? 15 : 14;       // groups g = x + 8j, g <= 112
    const int g0 = x + 8 * wave;
    const int j1 = wave + 8;
    const bool has1 = (j1 < J);
    const int g1 = x + 8 * (has1 ? j1 : 0);
    const u16* bp0 = A.gruwT + (size_t)(16 * g0 + l15) * 1216 + koff;
    const u16* bp1 = A.gruwT + (size_t)(16 * g1 + l15) * 1216 + koff;
    const int c0 = 16 * g0 + l15;                 // < 1024, always valid
    const int c1 = 16 * g1 + l15;
    const bool c1ok = has1 && (c1 < 1800);
    const float gb0 = A.grub[c0];
    const float gb1 = c1ok ? A.grub[c1] : 0.f;

    for (int t = 0; t < 64; ++t) {
      f32x4 p00{}, p01{}, p10{}, p11{};
      // ---- A1: deter K-half (k 608..1215); ready when deterF >= t ----
      if (tid == 0) {
        int it = 0;
        while ((int)min(fld(FD(2 * h)), fld(FD(2 * h + 1))) < t) {
          if (++it > POLL_CAP) break;
          __builtin_amdgcn_s_sleep(1);
        }
      }
      __syncthreads();
      for (int idx = tid; idx < 2432; idx += 512) {  // octets 76..151
        int r = idx / 76, o = idx - r * 76 + 76;
        *reinterpret_cast<short8*>(&stg[r][o * 8]) =
            ald16B(A.xd + (size_t)(r0 + r) * XDS + o * 8);
      }
      __syncthreads();
      for (int kk = 608; kk < 1216; kk += 32) {
        short8 a0 = *reinterpret_cast<const short8*>(&stg[l15][koff + kk]);
        short8 a1 = *reinterpret_cast<const short8*>(&stg[16 + l15][koff + kk]);
        short8 b0 = *reinterpret_cast<const short8*>(bp0 + kk);
        p00 = MF(a0, b0, p00);
        p01 = MF(a1, b0, p01);
        if (has1) {
          short8 b1 = *reinterpret_cast<const short8*>(bp1 + kk);
          p10 = MF(a0, b1, p10);
          p11 = MF(a1, b1, p11);
        }
      }
      // ---- A2: x K-half (k 0..607); ready when xF >= t ----
      if (tid == 0) {
        int it = 0;
        while ((int)min(fld(FX(2 * h)), fld(FX(2 * h + 1))) < t) {
          if (++it > POLL_CAP) break;
          __builtin_amdgcn_s_sleep(1);
        }
      }
      __syncthreads();
      for (int idx = tid; idx < 2432; idx += 512) {  // octets 0..75
        int r = idx / 76, o = idx - r * 76;
        *reinterpret_cast<short8*>(&stg[r][o * 8]) =
            ald16B(A.xd + (size_t)(r0 + r) * XDS + o * 8);
      }
      __syncthreads();
      for (int kk = 0; kk < 608; kk += 32) {
        short8 a0 = *reinterpret_cast<const short8*>(&stg[l15][koff + kk]);
        short8 a1 = *reinterpret_cast<const short8*>(&stg[16 + l15][koff + kk]);
        short8 b0 = *reinterpret_cast<const short8*>(bp0 + kk);
        p00 = MF(a0, b0, p00);
        p01 = MF(a1, b0, p01);
        if (has1) {
          short8 b1 = *reinterpret_cast<const short8*>(bp1 + kk);
          p10 = MF(a0, b1, p10);
          p11 = MF(a1, b1, p11);
        }
      }
      // ---- store parts (bf16 packed col-pairs, bias fused) ----
#pragma unroll
      for (int i = 0; i < 4; ++i) {
        unsigned h00 = f2bf(p00[i] + gb0);
        unsigned h10 = f2bf(p01[i] + gb0);
        unsigned o00 = (unsigned)__shfl_xor((int)h00, 1);
        unsigned o10 = (unsigned)__shfl_xor((int)h10, 1);
        unsigned h01 = f2bf(p10[i] + gb1);
        unsigned h11 = f2bf(p11[i] + gb1);
        unsigned o01 = (unsigned)__shfl_xor((int)h01, 1);
        unsigned o11 = (unsigned)__shfl_xor((int)h11, 1);
        if (!(lane & 1)) {
          ast32(A.parts + (size_t)(r0 + crow + i) * PN + c0, h00 | (o00 << 16));
          ast32(A.parts + (size_t)(r0 + 16 + crow + i) * PN + c0, h10 | (o10 << 16));
          if (c1ok) {
            ast32(A.parts + (size_t)(r0 + crow + i) * PN + c1, h01 | (o01 << 16));
            ast32(A.parts + (size_t)(r0 + 16 + crow + i) * PN + c1, h11 | (o11 << 16));
          }
        }
      }
      __syncthreads();  // drains vmcnt per wave -> stores MALL-visible
      if (tid == 0) fst(FA(fl), (unsigned)(t + 1));
    }
  } else {
    // ================= BD block: 16 rows R0..R0+15 =======================
    const int b = bid - 48, h = b >> 1;
    const int R0 = b * 16;
    u16 (*pl)[PN] = (u16(*)[PN])smem;                       // 57,856
    float (*dsh)[600] = (float(*)[600])(smem + 57856);      // 38,400
    u16 (*dl)[648] = (u16(*)[648])(smem + 96256);           // 20,736
    u16 (*hl)[616] = (u16(*)[616])(smem + 116992);          // 19,712
    float (*sl)[68] = (float(*)[68])(smem + 136704);        //  4,352
    u16 (*xa)[72] = (u16(*)[72])(smem + 141056);            //  2,304
    u16* es = (u16*)smem;                                   // overlay on pl

    for (int i = tid; i < 16 * 648; i += 512) ((u16*)dl)[i] = 0;
    for (int i = tid; i < 16 * 616; i += 512) ((u16*)hl)[i] = 0;
    for (int i = tid; i < 16 * 72; i += 512) ((u16*)xa)[i] = 0;
    for (int i = tid; i < 16 * 600; i += 512) ((float*)dsh)[i] = 0.f;

    for (int t = 0; t < 64; ++t) {
      {  // wait my half's 8 A-flags
        const unsigned tgt = (unsigned)(t + 1);
        __syncthreads();
        if (wave == 0) {
          int it = 0;
          for (;;) {
            unsigned v = (lane < 8) ? fld(FA(h * 8 + lane)) : tgt;
            if (__all((int)(v >= tgt))) break;
            if (++it > POLL_CAP) break;
            __builtin_amdgcn_s_sleep(1);
          }
        }
        __syncthreads();
      }
      // ---- bulk parts load: 16 rows x 1808 bf16 -> LDS ----
      for (int idx = tid; idx < 3616; idx += 512) {
        int r = idx / 226, o = (idx - r * 226) * 8;
        *reinterpret_cast<short8*>(&pl[r][o]) =
            ald16B(A.parts + (size_t)(R0 + r) * PN + o);
      }
      __syncthreads();
      // ---- LN + gates + deter (bias already fused into parts) ----
      for (int rb = 0; rb < 16; rb += 8) {
        const int rr = rb + wave;
        float s = 0.f;
        for (int j = lane; j < 1800; j += 64) s += bf2f(pl[rr][j]);
#pragma unroll
        for (int o = 32; o; o >>= 1) s += __shfl_xor(s, o);
        float m = s * (1.f / 1800.f);
        float q2 = 0.f;
        for (int j = lane; j < 1800; j += 64) {
          float d = bf2f(pl[rr][j]) - m;
          q2 += d * d;
        }
#pragma unroll
        for (int o = 32; o; o >>= 1) q2 += __shfl_xor(q2, o);
        float rstd = rsqrtf(q2 * (1.f / 1800.f) + 1e-5f);
        for (int j = lane; j < 600; j += 64) {
          float p0 = (bf2f(pl[rr][j]) - m) * rstd * A.lns[j] + A.lnb[j];
          float p1 = (bf2f(pl[rr][600 + j]) - m) * rstd * A.lns[600 + j] + A.lnb[600 + j];
          float p2 =
              (bf2f(pl[rr][1200 + j]) - m) * rstd * A.lns[1200 + j] + A.lnb[1200 + j];
          float r2 = sigf(p0);
          float cd = tanhf(r2 * p1);
          float u = sigf(p2 - 1.f);
          float dn = u * cd + (1.f - u) * dsh[rr][j];
          dsh[rr][j] = dn;
          dl[rr][j] = f2bf(dn);
          unsigned hv = f2bf(dn);
          unsigned ov = (unsigned)__shfl_xor((int)hv, 1);
          if (!(lane & 1))
            ast32(A.xd + (size_t)(R0 + rr) * XDS + 600 + j, hv | (ov << 16));
        }
      }
      __syncthreads();  // deter xd stores drained -> publish early
      if (tid == 0) fst(FD(b), (unsigned)(t + 1));
      // ---- off-critical-path: out/dall deter streams + epre stage ----
      for (int idx = tid; idx < 4800; idx += 512) {
        int r = idx / 300, j = (idx - r * 300) * 2;
        float f0 = dsh[r][j], f1 = dsh[r][j + 1];
        unsigned pk = (unsigned)f2bf(f0) | ((unsigned)f2bf(f1) << 16);
        size_t orow = (size_t)(R0 + r) * 64 + t;
        __builtin_nontemporal_store(pk, (unsigned*)(A.dall + orow * 640 + j));
        float* ob = A.out + orow * 1392;
        __builtin_nontemporal_store(f0, ob + 96 + j);
        __builtin_nontemporal_store(f1, ob + 97 + j);
        __builtin_nontemporal_store(f0, ob + 792 + j);
        __builtin_nontemporal_store(f1, ob + 793 + j);
      }
      if (tid < 320) {
        int r = tid / 20, qd = tid - r * 20;
        size_t orow = (size_t)(R0 + r) * 64 + t;
        __builtin_nontemporal_store(0u, (unsigned*)(A.dall + orow * 640 + 600 + 2 * qd));
      }
      for (int idx = tid; idx < 1200; idx += 512) {  // es overlays dead pl
        int r = idx / 75, ko2 = (idx - r * 75) * 8;
        short8 ev = __builtin_nontemporal_load(
            (const short8*)(A.epre + ((size_t)t * 192 + R0 + r) * 600 + ko2));
        *reinterpret_cast<short8*>(&es[r * 608 + ko2]) = ev;
      }
      __syncthreads();
      // ---- obs1: hl = elu(deter @ o1w + epre) ----
#pragma unroll
      for (int s2 = 0; s2 < 5; ++s2) {
        int g2 = wave + 8 * s2;
        if (g2 < 38) {
          const u16* bp = A.o1wT + (size_t)(g2 * 16 + l15) * 608 + koff;
          f32x4 ac{};
          for (int kk = 0; kk < 608; kk += 32)
            ac = MF(*reinterpret_cast<const short8*>(&dl[l15][koff + kk]),
                    *reinterpret_cast<const short8*>(bp + kk), ac);
          int cw = g2 * 16 + l15;
          if (cw < 600) {
#pragma unroll
            for (int i = 0; i < 4; ++i) {
              int r = crow + i;
              hl[r][cw] = f2bf(eluf(ac[i] + bf2f(es[r * 608 + cw])));
            }
          }
        }
      }
      __syncthreads();
      // ---- obs2 (waves 0-3) ----
      if (wave < 4) {
        const int n0 = wave * 16;
        const u16* bp = A.o2wT + (size_t)(n0 + l15) * 608 + koff;
        f32x4 ac{};
        for (int kk = 0; kk < 608; kk += 32)
          ac = MF(*reinterpret_cast<const short8*>(&hl[l15][koff + kk]),
                  *reinterpret_cast<const short8*>(bp + kk), ac);
#pragma unroll
        for (int i = 0; i < 4; ++i)
          sl[crow + i][n0 + l15] = ac[i] + A.obs2b[n0 + l15];
      }
      __syncthreads();
      // ---- head outputs + stoch + xa ----
      {
        int r = tid >> 5, j = tid & 31;
        size_t orow = (size_t)(R0 + r) * 64 + t;
        float mean = sl[r][j];
        float sd = 2.f * sigf(0.5f * sl[r][32 + j]) + 0.1f;
        float st =
            mean + sd * __builtin_nontemporal_load((const float*)&A.npo[orow * 32 + j]);
        float* ob = A.out + orow * 1392;
        __builtin_nontemporal_store(mean, ob + j);
        __builtin_nontemporal_store(sd, ob + 32 + j);
        __builtin_nontemporal_store(st, ob + 64 + j);
        xa[r][j] = f2bf(st);
      }
      if (tid < 256) {
        int r = tid >> 4, a2 = tid & 15;
        float av =
            (t < 63)
                ? __builtin_nontemporal_load(
                      (const float*)&A.action[((size_t)(R0 + r) * 64 + t + 1) * 16 + a2])
                : 0.f;
        xa[r][32 + a2] = f2bf(av);
      }
      __syncthreads();
      // ---- img1 -> x(t+1) -> xd ----
      if (t < 63) {
#pragma unroll
        for (int s2 = 0; s2 < 5; ++s2) {
          int g2 = wave + 8 * s2;
          if (g2 < 38) {
            const u16* bp = A.w1pT + (size_t)(g2 * 16 + l15) * 64 + koff;
            f32x4 ax{};
            ax = MF(*reinterpret_cast<const short8*>(&xa[l15][koff]),
                    *reinterpret_cast<const short8*>(bp), ax);
            ax = MF(*reinterpret_cast<const short8*>(&xa[l15][32 + koff]),
                    *reinterpret_cast<const short8*>(bp + 32), ax);
            int cx = g2 * 16 + l15;
            float bi = (cx < 600) ? A.img1b[cx] : 0.f;
#pragma unroll
            for (int i = 0; i < 4; ++i) {
              unsigned hv = f2bf(eluf(ax[i] + bi));
              unsigned ov = (unsigned)__shfl_xor((int)hv, 1);
              if (!(lane & 1) && cx < 600)
                ast32(A.xd + (size_t)(R0 + crow + i) * XDS + cx, hv | (ov << 16));
            }
          }
        }
        __syncthreads();  // x stores drained
        if (tid == 0) fst(FX(b), (unsigned)(t + 1));
      }
    }
  }
}

// ---------------- launch ----------------
extern "C" void kernel_launch(void* const* d_in, const int* in_sizes, int n_in,
                              void* d_out, int out_size, void* d_ws, size_t ws_size,
                              hipStream_t stream) {
  (void)in_sizes; (void)n_in; (void)out_size; (void)ws_size;
  const float* action = (const float*)d_in[0];
  const float* embed = (const float*)d_in[1];
  const float* npr = (const float*)d_in[2];
  const float* npo = (const float*)d_in[3];
  const float* img1w = (const float*)d_in[4];
  const float* img1b = (const float*)d_in[5];
  const float* gruw = (const float*)d_in[6];
  const float* grub = (const float*)d_in[7];
  const float* lns = (const float*)d_in[8];
  const float* lnb = (const float*)d_in[9];
  const float* img2w = (const float*)d_in[10];
  const float* img2b = (const float*)d_in[11];
  const float* img3w = (const float*)d_in[12];
  const float* img3b = (const float*)d_in[13];
  const float* obs1w = (const float*)d_in[14];
  const float* obs1b = (const float*)d_in[15];
  const float* obs2w = (const float*)d_in[16];
  const float* obs2b = (const float*)d_in[17];
  float* out = (float*)d_out;
  char* ws = (char*)d_ws;

  size_t off = 0;
  auto alloc = [&](size_t bytes) {
    size_t o = off;
    off += (bytes + 255) & ~(size_t)255;
    return o;
  };
  size_t o_flags = alloc(6912 * 4);
  size_t o_embed = alloc(12288ull * 1024 * 2);  // reused as dall (12288x640)
  size_t o_epre = alloc(12288ull * 600 * 2);    // reused (with o_wemb) as h_img
  size_t o_wemb = alloc(1024ull * 600 * 2);
  size_t o_gruwT = alloc(1808ull * 1216 * 2);
  size_t o_o1wT = alloc(608ull * 608 * 2);
  size_t o_o2wT = alloc(64ull * 608 * 2);
  size_t o_w1pT = alloc(640ull * 64 * 2);
  size_t o_i2w = alloc(640ull * 600 * 2);
  size_t o_i3w = alloc(640ull * 64 * 2);
  size_t o_xd = alloc(192ull * XDS * 2);
  size_t o_parts = alloc(192ull * PN * 2);

  unsigned* flags = (unsigned*)(ws + o_flags);
  u16* embed_bf = (u16*)(ws + o_embed);
  u16* dall = (u16*)(ws + o_embed);
  u16* epre = (u16*)(ws + o_epre);
  u16* himg = (u16*)(ws + o_epre);
  u16* wemb = (u16*)(ws + o_wemb);
  u16* gruwT = (u16*)(ws + o_gruwT);
  u16* o1wT = (u16*)(ws + o_o1wT);
  u16* o2wT = (u16*)(ws + o_o2wT);
  u16* w1pT = (u16*)(ws + o_w1pT);
  u16* i2wb = (u16*)(ws + o_i2w);
  u16* i3wb = (u16*)(ws + o_i3w);
  u16* xd = (u16*)(ws + o_xd);
  u16* parts = (u16*)(ws + o_parts);

  auto cgr = [](size_t total) {
    size_t g = (total + 255) / 256;
    return (unsigned)(g > 4096 ? 4096 : g);
  };

  // setup conversions
  conv_pad<<<cgr(12288ull * 1024), 256, 0, stream>>>(embed, embed_bf, 12288, 1024, 12288, 0);
  conv_pad<<<cgr(1024ull * 600), 256, 0, stream>>>(obs1w, wemb, 1024, 600, 1024, 600);
  conv_pad<<<cgr(640ull * 600), 256, 0, stream>>>(img2w, i2wb, 600, 600, 640, 0);
  conv_pad<<<cgr(640ull * 64), 256, 0, stream>>>(img3w, i3wb, 600, 64, 640, 0);
  conv_T<<<cgr(1808ull * 1216), 256, 0, stream>>>(gruw, gruwT, 1200, 1800, 1216, 1808);
  conv_T<<<cgr(608ull * 608), 256, 0, stream>>>(obs1w, o1wT, 600, 600, 608, 608);
  conv_T<<<cgr(64ull * 608), 256, 0, stream>>>(obs2w, o2wT, 600, 64, 608, 64);
  conv_T<<<cgr(640ull * 64), 256, 0, stream>>>(img1w, w1pT, 48, 600, 64, 640);

  k_init<<<192, 256, 0, stream>>>(action, img1w, img1b, xd, flags);

  // epre[t][b][600] = embed @ obs1_w[600:,:] + obs1_b   (bf16, t-major)
  gemm64<4><<<dim3(10, 192), 256, 0, stream>>>(embed_bf, 1024, wemb, 600, obs1b,
                                               epre, 600, 600, 600, 1024);

  // scan: 48 XCD-pinned A-blocks + 12 BD-blocks, point-to-point flags
  ScanArgs sa;
  sa.xd = xd; sa.parts = parts;
  sa.gruwT = gruwT; sa.grub = grub; sa.lns = lns; sa.lnb = lnb;
  sa.dall = dall; sa.out = out;
  sa.o1wT = o1wT; sa.epre = epre;
  sa.o2wT = o2wT; sa.obs2b = obs2b; sa.npo = npo;
  sa.w1pT = w1pT; sa.img1b = img1b; sa.action = action;
  sa.flags = flags;
  scan64<<<60, 512, 0, stream>>>(sa);

  // batched prior: h_img = elu(deter_all @ img2_w + img2_b), then img3 head
  gemm64<2><<<dim3(10, 192), 256, 0, stream>>>(dall, 640, i2wb, 600, img2b,
                                               himg, 640, 640, 600, 640);
  head_prior<<<192, 256, 0, stream>>>(himg, i3wb, img3b, npr, out);
}

// Round 15
// 3095.531 us; speedup vs baseline: 2.2128x; 1.1776x over previous
//
#include <hip/hip_runtime.h>

typedef unsigned short u16;
typedef __attribute__((ext_vector_type(8))) short short8;
typedef __attribute__((ext_vector_type(4))) float f32x4;

#define DEV __device__ __forceinline__

// B=192, T=64, ACT=16, EMB=1024, STOCH=32, DETER=600, HID=600
// out row stride 1392: [mean_po 0, std_po 32, stoch_po 64, deter 96,
//                       mean_pr 696, std_pr 728, stoch_pr 760, deter 792]
// xd row [192][1280]: [x 0..599 | deter 600..1199 | pad 1200..1279]
#define XDS 1280
#define PN 1808        // parts bf16 row stride
#define POLL_CAP 65536

DEV u16 f2bf(float f) {
  unsigned u = __float_as_uint(f);
  u = (u + 0x7FFFu + ((u >> 16) & 1u)) >> 16;
  return (u16)u;
}
DEV float bf2f(u16 h) { return __uint_as_float(((unsigned)h) << 16); }
DEV float sigf(float x) { return 1.f / (1.f + __expf(-x)); }
DEV float eluf(float x) { return x > 0.f ? x : __expf(x) - 1.f; }
DEV f32x4 MF(short8 a, short8 b, f32x4 c) {
  return __builtin_amdgcn_mfma_f32_16x16x32_bf16(a, b, c, 0, 0, 0);
}

// ---- device-scope (MALL-coherent) helpers — r5..r14 replay-validated ----
DEV unsigned long long ald64(const void* p) {
  return __hip_atomic_load((const unsigned long long*)p, __ATOMIC_RELAXED,
                           __HIP_MEMORY_SCOPE_AGENT);
}
DEV short8 ald16B(const u16* p) {
  union { unsigned long long u[2]; short8 v; } x;
  x.u[0] = ald64(p);
  x.u[1] = ald64(p + 4);
  return x.v;
}
DEV void ast32(void* p, unsigned v) {
  __hip_atomic_store((unsigned*)p, v, __ATOMIC_RELAXED, __HIP_MEMORY_SCOPE_AGENT);
}
DEV unsigned fld(const unsigned* p) {
  return __hip_atomic_load(p, __ATOMIC_RELAXED, __HIP_MEMORY_SCOPE_AGENT);
}
DEV void fst(unsigned* p, unsigned v) {
  __hip_atomic_store(p, v, __ATOMIC_RELAXED, __HIP_MEMORY_SCOPE_AGENT);
}

// ---------------- f32 -> bf16 with zero row padding (k-major) ----------------
__global__ __launch_bounds__(256) void conv_pad(const float* __restrict__ src,
                                                u16* __restrict__ dst,
                                                int K, int N, int Kpad, int srcRowOff) {
  size_t total = (size_t)Kpad * N;
  for (size_t idx = (size_t)blockIdx.x * 256 + threadIdx.x; idx < total;
       idx += (size_t)gridDim.x * 256) {
    int k = (int)(idx / (size_t)N);
    int n = (int)(idx % (size_t)N);
    dst[idx] = (k < K) ? f2bf(src[(size_t)(k + srcRowOff) * N + n]) : (u16)0;
  }
}

// ---------------- f32 [K0][N0] -> bf16 transposed [Npad][Kpad] ----------------
__global__ __launch_bounds__(256) void conv_T(const float* __restrict__ src,
                                              u16* __restrict__ dst,
                                              int K0, int N0, int Kpad, int Npad) {
  size_t total = (size_t)Npad * Kpad;
  for (size_t idx = (size_t)blockIdx.x * 256 + threadIdx.x; idx < total;
       idx += (size_t)gridDim.x * 256) {
    int n = (int)(idx / (size_t)Kpad);
    int k = (int)(idx % (size_t)Kpad);
    dst[idx] = (k < K0 && n < N0) ? f2bf(src[(size_t)k * N0 + n]) : (u16)0;
  }
}

// ---------------- MFMA 64x64 tile core (setup/tail GEMMs) ----
DEV void mfma_tile(const u16 (*As)[72], const u16 (*Bs)[72], int wm, int wn,
                   int lane, f32x4 acc[2][2]) {
#pragma unroll
  for (int s = 0; s < 2; ++s) {
    const int ko = s * 32 + ((lane >> 4) << 3);
    short8 a0 = *reinterpret_cast<const short8*>(&As[wm + (lane & 15)][ko]);
    short8 a1 = *reinterpret_cast<const short8*>(&As[wm + 16 + (lane & 15)][ko]);
    short8 b0 = *reinterpret_cast<const short8*>(&Bs[wn + (lane & 15)][ko]);
    short8 b1 = *reinterpret_cast<const short8*>(&Bs[wn + 16 + (lane & 15)][ko]);
    acc[0][0] = MF(a0, b0, acc[0][0]);
    acc[0][1] = MF(a0, b1, acc[0][1]);
    acc[1][0] = MF(a1, b0, acc[1][0]);
    acc[1][1] = MF(a1, b1, acc[1][1]);
  }
}

// ---------------- generic 64x64-tiled bf16 GEMM (setup/tail) ----------------
// EPI: 2 = +bias, elu, bf16 out ; 4 = +bias, bf16 out, epre-permuted store
template <int EPI>
__global__ __launch_bounds__(256) void gemm64(
    const u16* __restrict__ A, int lda, const u16* __restrict__ W, int ldw,
    const float* __restrict__ bias, void* __restrict__ Cv, int ldc,
    int Nstore, int N, int K) {
  __shared__ u16 As[64][72];
  __shared__ u16 Bs[64][72];
  const int tid = threadIdx.x, lane = tid & 63, wave = tid >> 6;
  const int wm = (wave & 1) * 32, wn = (wave >> 1) * 32;
  const int bn0 = blockIdx.x * 64, bm0 = blockIdx.y * 64;
  const int am = tid >> 2, ak0 = (tid & 3) * 16;
  const int bk = tid >> 3, bn = (tid & 7) * 8;

  f32x4 acc[2][2] = {};
  for (int k0 = 0; k0 < K; k0 += 64) {
    __syncthreads();
    {
      const u16* src = A + (size_t)(bm0 + am) * lda + k0 + ak0;
      *reinterpret_cast<short8*>(&As[am][ak0]) = *reinterpret_cast<const short8*>(src);
      *reinterpret_cast<short8*>(&As[am][ak0 + 8]) = *reinterpret_cast<const short8*>(src + 8);
    }
    {
      int gn = bn0 + bn;
#pragma unroll
      for (int h = 0; h < 2; ++h) {
        int kk = k0 + bk + h * 32;
        short8 v;
        if (gn + 7 < N) {
          v = *reinterpret_cast<const short8*>(W + (size_t)kk * ldw + gn);
        } else {
          for (int j = 0; j < 8; ++j)
            v[j] = (gn + j < N) ? (short)W[(size_t)kk * ldw + gn + j] : (short)0;
        }
#pragma unroll
        for (int j = 0; j < 8; ++j) Bs[bn + j][bk + h * 32] = (u16)v[j];
      }
    }
    __syncthreads();
    mfma_tile(As, Bs, wm, wn, lane, acc);
  }

#pragma unroll
  for (int r = 0; r < 2; ++r)
#pragma unroll
    for (int c = 0; c < 2; ++c)
#pragma unroll
      for (int i = 0; i < 4; ++i) {
        int grow = bm0 + wm + r * 16 + ((lane >> 4) << 2) + i;
        int gcol = bn0 + wn + c * 16 + (lane & 15);
        if (gcol >= Nstore) continue;
        bool ok = gcol < N;
        float v = acc[r][c][i] + (ok ? bias[gcol] : 0.f);
        if (EPI == 2) {
          v = eluf(v);
          ((u16*)Cv)[(size_t)grow * ldc + gcol] = ok ? f2bf(v) : (u16)0;
        } else {  // EPI 4: epre[t][b][600] layout
          size_t row2 = (size_t)(grow & 63) * 192 + (size_t)(grow >> 6);
          ((u16*)Cv)[row2 * 600 + gcol] = f2bf(v);
        }
      }
}

// ------- init: x(t=0)=elu(action part), deter=0, pads=0, flags=0 ----------
__global__ __launch_bounds__(256) void k_init(const float* __restrict__ action,
                                              const float* __restrict__ img1w,
                                              const float* __restrict__ img1b,
                                              u16* __restrict__ xd,
                                              unsigned* __restrict__ flags) {
  __shared__ float act[16];
  int b = blockIdx.x, tid = threadIdx.x;
  if (b == 0)
    for (int i = tid; i < 6912; i += 256) flags[i] = 0;
  if (tid < 16) act[tid] = action[(size_t)b * 64 * 16 + tid];  // t = 0
  __syncthreads();
  for (int h = tid; h < 600; h += 256) {
    float s = img1b[h];
#pragma unroll
    for (int a = 0; a < 16; ++a) s += act[a] * img1w[(size_t)(32 + a) * 600 + h];
    xd[(size_t)b * XDS + h] = f2bf(eluf(s));
  }
  for (int j = tid; j < 680; j += 256) xd[(size_t)b * XDS + 600 + j] = 0;
}

// ---------------- batched prior head (tail; N=64 GEMM + dist outputs) --------
__global__ __launch_bounds__(256) void head_prior(
    const u16* __restrict__ A, const u16* __restrict__ W,
    const float* __restrict__ bias64, const float* __restrict__ noise,
    float* __restrict__ out) {
  __shared__ u16 As[64][72];
  __shared__ u16 Bs[64][72];
  __shared__ float sl[64][68];
  const int tid = threadIdx.x, lane = tid & 63, wave = tid >> 6;
  const int wm = (wave & 1) * 32, wn = (wave >> 1) * 32;
  const int bm0 = blockIdx.x * 64;
  const int am = tid >> 2, ak0 = (tid & 3) * 16;
  const int bk = tid >> 3, bn = (tid & 7) * 8;

  f32x4 acc[2][2] = {};
  for (int k0 = 0; k0 < 640; k0 += 64) {
    __syncthreads();
    {
      const u16* src = A + (size_t)(bm0 + am) * 640 + k0 + ak0;
      *reinterpret_cast<short8*>(&As[am][ak0]) = *reinterpret_cast<const short8*>(src);
      *reinterpret_cast<short8*>(&As[am][ak0 + 8]) = *reinterpret_cast<const short8*>(src + 8);
    }
#pragma unroll
    for (int h = 0; h < 2; ++h) {
      int kk = k0 + bk + h * 32;
      short8 v = *reinterpret_cast<const short8*>(W + (size_t)kk * 64 + bn);
#pragma unroll
      for (int j = 0; j < 8; ++j) Bs[bn + j][bk + h * 32] = (u16)v[j];
    }
    __syncthreads();
    mfma_tile(As, Bs, wm, wn, lane, acc);
  }
#pragma unroll
  for (int r = 0; r < 2; ++r)
#pragma unroll
    for (int c = 0; c < 2; ++c)
#pragma unroll
      for (int i = 0; i < 4; ++i) {
        int col = wn + c * 16 + (lane & 15);
        sl[wm + r * 16 + ((lane >> 4) << 2) + i][col] = acc[r][c][i] + bias64[col];
      }
  __syncthreads();
  for (int task = tid; task < 64 * 32; task += 256) {
    int r = task >> 5, j = task & 31;
    size_t orow = (size_t)(bm0 + r);
    size_t base = orow * 1392 + 696;
    float mean = sl[r][j];
    float sd = 2.f * sigf(0.5f * sl[r][32 + j]) + 0.1f;
    float st = mean + sd * noise[orow * 32 + j];
    out[base + j] = mean;
    out[base + 32 + j] = sd;
    out[base + 64 + j] = st;
  }
}

// ---- scan: 6 pipelines of {8 XCD-pinned A-blocks -> 2 BD-blocks}, all blocks
// ---- 1024 threads (16 waves). A-block (h,x): rows h*32..+31, one 16-col group
// ---- per wave (g = x + 8*wave). Split-K: deter half after deterF, x half
// ---- after xF. BD-block b: per-wave pipelined parts gather, LN 1 row/wave,
// ---- obs1/img1 in 3 rounds. Flags: A 0..47, xF 64+b, dF 96+b (256B apart).
struct ScanArgs {
  u16* xd;            // [192][1280] carry
  u16* parts;         // [192][PN] bf16 (bias fused)
  const u16* gruwT;   // [1808][1216] (cached, L2-resident per XCD slice)
  const float* grub;
  const float* lns;
  const float* lnb;
  u16* dall;          // [12288][640] (nt; read by tail)
  float* out;
  const u16* o1wT;    // [608][608]
  const u16* epre;    // [64][192][600] (t-major, nt loads)
  const u16* o2wT;    // [64][608]
  const float* obs2b;
  const float* npo;
  const u16* w1pT;    // [640][64]
  const float* img1b;
  const float* action;
  unsigned* flags;
};

__global__ __launch_bounds__(1024, 1) void scan64(ScanArgs A) {
  const int bid = blockIdx.x, tid = threadIdx.x;
  const int lane = tid & 63, wave = tid >> 6;
  const int l15 = lane & 15;
  const int koff = (lane >> 4) << 3;   // k-octet offset within 32-k slab
  const int crow = (lane >> 4) << 2;   // C-row base within 16
  __shared__ __align__(16) char smem[143360];
  unsigned* F = A.flags;

  auto FA = [&](int idx) { return F + (size_t)idx * 64; };
  auto FX = [&](int b2) { return F + (size_t)(64 + b2) * 64; };
  auto FD = [&](int b2) { return F + (size_t)(96 + b2) * 64; };

  if (bid < 48) {
    // ================= A block: h = 32-row half, x = XCD col-comb ==========
    u16 (*stg)[1224] = (u16(*)[1224])smem;  // 32 x 1224 = 78,336 B
    const int h = bid >> 3, x = bid & 7;
    const int r0 = h * 32;
    const int fl = h * 8 + x;
    const int J = (x == 0) ? 15 : 14;       // wave w < J owns group g = x + 8w
    const bool hasg = (wave < J);
    const int g0 = x + 8 * (hasg ? wave : 0);
    const u16* bp0 = A.gruwT + (size_t)(16 * g0 + l15) * 1216 + koff;
    const int c0 = 16 * g0 + l15;
    const bool c0ok = hasg && (c0 < 1800);
    const float gb0 = c0ok ? A.grub[c0] : 0.f;

    for (int t = 0; t < 64; ++t) {
      f32x4 p00{}, p01{};
      // ---- A1: deter K-half (k 608..1215); ready when deterF >= t ----
      if (tid == 0) {
        int it = 0;
        while ((int)min(fld(FD(2 * h)), fld(FD(2 * h + 1))) < t) {
          if (++it > POLL_CAP) break;
          __builtin_amdgcn_s_sleep(1);
        }
      }
      __syncthreads();
      for (int idx = tid; idx < 2432; idx += 1024) {  // octets 76..151
        int r = idx / 76, o = idx - r * 76 + 76;
        *reinterpret_cast<short8*>(&stg[r][o * 8]) =
            ald16B(A.xd + (size_t)(r0 + r) * XDS + o * 8);
      }
      __syncthreads();
      if (hasg) {
        for (int kk = 608; kk < 1216; kk += 32) {
          short8 a0 = *reinterpret_cast<const short8*>(&stg[l15][koff + kk]);
          short8 a1 = *reinterpret_cast<const short8*>(&stg[16 + l15][koff + kk]);
          short8 b0 = *reinterpret_cast<const short8*>(bp0 + kk);
          p00 = MF(a0, b0, p00);
          p01 = MF(a1, b0, p01);
        }
      }
      // ---- A2: x K-half (k 0..607); ready when xF >= t ----
      if (tid == 0) {
        int it = 0;
        while ((int)min(fld(FX(2 * h)), fld(FX(2 * h + 1))) < t) {
          if (++it > POLL_CAP) break;
          __builtin_amdgcn_s_sleep(1);
        }
      }
      __syncthreads();
      for (int idx = tid; idx < 2432; idx += 1024) {  // octets 0..75
        int r = idx / 76, o = idx - r * 76;
        *reinterpret_cast<short8*>(&stg[r][o * 8]) =
            ald16B(A.xd + (size_t)(r0 + r) * XDS + o * 8);
      }
      __syncthreads();
      if (hasg) {
        for (int kk = 0; kk < 608; kk += 32) {
          short8 a0 = *reinterpret_cast<const short8*>(&stg[l15][koff + kk]);
          short8 a1 = *reinterpret_cast<const short8*>(&stg[16 + l15][koff + kk]);
          short8 b0 = *reinterpret_cast<const short8*>(bp0 + kk);
          p00 = MF(a0, b0, p00);
          p01 = MF(a1, b0, p01);
        }
        // ---- store parts (bf16 packed col-pairs, bias fused) ----
        if (c0ok) {
#pragma unroll
          for (int i = 0; i < 4; ++i) {
            unsigned h00 = f2bf(p00[i] + gb0);
            unsigned h10 = f2bf(p01[i] + gb0);
            unsigned o00 = (unsigned)__shfl_xor((int)h00, 1);
            unsigned o10 = (unsigned)__shfl_xor((int)h10, 1);
            if (!(lane & 1)) {
              ast32(A.parts + (size_t)(r0 + crow + i) * PN + c0, h00 | (o00 << 16));
              ast32(A.parts + (size_t)(r0 + 16 + crow + i) * PN + c0, h10 | (o10 << 16));
            }
          }
        }
      }
      __syncthreads();  // drains vmcnt per wave -> stores MALL-visible
      if (tid == 0) fst(FA(fl), (unsigned)(t + 1));
    }
  } else {
    // ================= BD block: 16 rows R0..R0+15, 16 waves ===============
    const int b = bid - 48, h = b >> 1;
    const int R0 = b * 16;
    u16 (*pl)[PN] = (u16(*)[PN])smem;                       // 57,856
    float (*dsh)[600] = (float(*)[600])(smem + 57856);      // 38,400
    u16 (*dl)[648] = (u16(*)[648])(smem + 96256);           // 20,736
    u16 (*hl)[616] = (u16(*)[616])(smem + 116992);          // 19,712
    float (*sl)[68] = (float(*)[68])(smem + 136704);        //  4,352
    u16 (*xa)[72] = (u16(*)[72])(smem + 141056);            //  2,304
    u16* es = (u16*)smem;                                   // overlay on pl

    for (int i = tid; i < 16 * 648; i += 1024) ((u16*)dl)[i] = 0;
    for (int i = tid; i < 16 * 616; i += 1024) ((u16*)hl)[i] = 0;
    for (int i = tid; i < 16 * 72; i += 1024) ((u16*)xa)[i] = 0;
    for (int i = tid; i < 16 * 600; i += 1024) ((float*)dsh)[i] = 0.f;

    for (int t = 0; t < 64; ++t) {
      // ---- per-wave pipelined parts gather: wave w polls producer (w&7) and
      // ---- loads its 8-row x slice immediately ----
      {
        const unsigned tgt = (unsigned)(t + 1);
        const int fw = wave & 7;
        const int rlo = (wave < 8) ? 0 : 8;
        int it = 0;
        while (fld(FA(h * 8 + fw)) < tgt) {
          if (++it > POLL_CAP) break;
          __builtin_amdgcn_s_sleep(1);
        }
        const int J2 = (fw == 0) ? 15 : 14;
        for (int task = lane; task < J2 * 16; task += 64) {
          int j2 = task >> 4;
          int r2 = (task >> 1) & 7, hf = task & 1;
          int col = 16 * (fw + 8 * j2) + hf * 8;
          *reinterpret_cast<short8*>(&pl[rlo + r2][col]) =
              ald16B(A.parts + (size_t)(R0 + rlo + r2) * PN + col);
        }
      }
      __syncthreads();
      // ---- LN + gates + deter: one row per wave (bias fused in parts) ----
      {
        const int rr = wave;
        float s = 0.f;
        for (int j = lane; j < 1800; j += 64) s += bf2f(pl[rr][j]);
#pragma unroll
        for (int o = 32; o; o >>= 1) s += __shfl_xor(s, o);
        float m = s * (1.f / 1800.f);
        float q2 = 0.f;
        for (int j = lane; j < 1800; j += 64) {
          float d = bf2f(pl[rr][j]) - m;
          q2 += d * d;
        }
#pragma unroll
        for (int o = 32; o; o >>= 1) q2 += __shfl_xor(q2, o);
        float rstd = rsqrtf(q2 * (1.f / 1800.f) + 1e-5f);
        for (int j = lane; j < 600; j += 64) {
          float p0 = (bf2f(pl[rr][j]) - m) * rstd * A.lns[j] + A.lnb[j];
          float p1 = (bf2f(pl[rr][600 + j]) - m) * rstd * A.lns[600 + j] + A.lnb[600 + j];
          float p2 =
              (bf2f(pl[rr][1200 + j]) - m) * rstd * A.lns[1200 + j] + A.lnb[1200 + j];
          float r2 = sigf(p0);
          float cd = tanhf(r2 * p1);
          float u = sigf(p2 - 1.f);
          float dn = u * cd + (1.f - u) * dsh[rr][j];
          dsh[rr][j] = dn;
          dl[rr][j] = f2bf(dn);
          unsigned hv = f2bf(dn);
          unsigned ov = (unsigned)__shfl_xor((int)hv, 1);
          if (!(lane & 1))
            ast32(A.xd + (size_t)(R0 + rr) * XDS + 600 + j, hv | (ov << 16));
        }
      }
      __syncthreads();  // deter xd stores drained -> publish early
      if (tid == 0) fst(FD(b), (unsigned)(t + 1));
      // ---- off-critical-path: out/dall deter streams + epre stage ----
      for (int idx = tid; idx < 4800; idx += 1024) {
        int r = idx / 300, j = (idx - r * 300) * 2;
        float f0 = dsh[r][j], f1 = dsh[r][j + 1];
        unsigned pk = (unsigned)f2bf(f0) | ((unsigned)f2bf(f1) << 16);
        size_t orow = (size_t)(R0 + r) * 64 + t;
        __builtin_nontemporal_store(pk, (unsigned*)(A.dall + orow * 640 + j));
        float* ob = A.out + orow * 1392;
        __builtin_nontemporal_store(f0, ob + 96 + j);
        __builtin_nontemporal_store(f1, ob + 97 + j);
        __builtin_nontemporal_store(f0, ob + 792 + j);
        __builtin_nontemporal_store(f1, ob + 793 + j);
      }
      if (tid < 320) {
        int r = tid / 20, qd = tid - r * 20;
        size_t orow = (size_t)(R0 + r) * 64 + t;
        __builtin_nontemporal_store(0u, (unsigned*)(A.dall + orow * 640 + 600 + 2 * qd));
      }
      for (int idx = tid; idx < 1200; idx += 1024) {  // es overlays dead pl
        int r = idx / 75, ko2 = (idx - r * 75) * 8;
        short8 ev = __builtin_nontemporal_load(
            (const short8*)(A.epre + ((size_t)t * 192 + R0 + r) * 600 + ko2));
        *reinterpret_cast<short8*>(&es[r * 608 + ko2]) = ev;
      }
      __syncthreads();
      // ---- obs1: hl = elu(deter @ o1w + epre)  (3 rounds over 16 waves) ----
#pragma unroll
      for (int s2 = 0; s2 < 3; ++s2) {
        int g2 = wave + 16 * s2;
        if (g2 < 38) {
          const u16* bp = A.o1wT + (size_t)(g2 * 16 + l15) * 608 + koff;
          f32x4 ac{};
          for (int kk = 0; kk < 608; kk += 32)
            ac = MF(*reinterpret_cast<const short8*>(&dl[l15][koff + kk]),
                    *reinterpret_cast<const short8*>(bp + kk), ac);
          int cw = g2 * 16 + l15;
          if (cw < 600) {
#pragma unroll
            for (int i = 0; i < 4; ++i) {
              int r = crow + i;
              hl[r][cw] = f2bf(eluf(ac[i] + bf2f(es[r * 608 + cw])));
            }
          }
        }
      }
      __syncthreads();
      // ---- obs2 (waves 0-3) ----
      if (wave < 4) {
        const int n0 = wave * 16;
        const u16* bp = A.o2wT + (size_t)(n0 + l15) * 608 + koff;
        f32x4 ac{};
        for (int kk = 0; kk < 608; kk += 32)
          ac = MF(*reinterpret_cast<const short8*>(&hl[l15][koff + kk]),
                  *reinterpret_cast<const short8*>(bp + kk), ac);
#pragma unroll
        for (int i = 0; i < 4; ++i)
          sl[crow + i][n0 + l15] = ac[i] + A.obs2b[n0 + l15];
      }
      __syncthreads();
      // ---- head outputs + stoch + xa ----
      if (tid < 512) {
        int r = tid >> 5, j = tid & 31;
        size_t orow = (size_t)(R0 + r) * 64 + t;
        float mean = sl[r][j];
        float sd = 2.f * sigf(0.5f * sl[r][32 + j]) + 0.1f;
        float st =
            mean + sd * __builtin_nontemporal_load((const float*)&A.npo[orow * 32 + j]);
        float* ob = A.out + orow * 1392;
        __builtin_nontemporal_store(mean, ob + j);
        __builtin_nontemporal_store(sd, ob + 32 + j);
        __builtin_nontemporal_store(st, ob + 64 + j);
        xa[r][j] = f2bf(st);
      } else if (tid < 768) {
        int r = (tid - 512) >> 4, a2 = tid & 15;
        float av =
            (t < 63)
                ? __builtin_nontemporal_load(
                      (const float*)&A.action[((size_t)(R0 + r) * 64 + t + 1) * 16 + a2])
                : 0.f;
        xa[r][32 + a2] = f2bf(av);
      }
      __syncthreads();
      // ---- img1 -> x(t+1) -> xd  (3 rounds over 16 waves) ----
      if (t < 63) {
#pragma unroll
        for (int s2 = 0; s2 < 3; ++s2) {
          int g2 = wave + 16 * s2;
          if (g2 < 38) {
            const u16* bp = A.w1pT + (size_t)(g2 * 16 + l15) * 64 + koff;
            f32x4 ax{};
            ax = MF(*reinterpret_cast<const short8*>(&xa[l15][koff]),
                    *reinterpret_cast<const short8*>(bp), ax);
            ax = MF(*reinterpret_cast<const short8*>(&xa[l15][32 + koff]),
                    *reinterpret_cast<const short8*>(bp + 32), ax);
            int cx = g2 * 16 + l15;
            float bi = (cx < 600) ? A.img1b[cx] : 0.f;
#pragma unroll
            for (int i = 0; i < 4; ++i) {
              unsigned hv = f2bf(eluf(ax[i] + bi));
              unsigned ov = (unsigned)__shfl_xor((int)hv, 1);
              if (!(lane & 1) && cx < 600)
                ast32(A.xd + (size_t)(R0 + crow + i) * XDS + cx, hv | (ov << 16));
            }
          }
        }
        __syncthreads();  // x stores drained
        if (tid == 0) fst(FX(b), (unsigned)(t + 1));
      }
    }
  }
}

// ---------------- launch ----------------
extern "C" void kernel_launch(void* const* d_in, const int* in_sizes, int n_in,
                              void* d_out, int out_size, void* d_ws, size_t ws_size,
                              hipStream_t stream) {
  (void)in_sizes; (void)n_in; (void)out_size; (void)ws_size;
  const float* action = (const float*)d_in[0];
  const float* embed = (const float*)d_in[1];
  const float* npr = (const float*)d_in[2];
  const float* npo = (const float*)d_in[3];
  const float* img1w = (const float*)d_in[4];
  const float* img1b = (const float*)d_in[5];
  const float* gruw = (const float*)d_in[6];
  const float* grub = (const float*)d_in[7];
  const float* lns = (const float*)d_in[8];
  const float* lnb = (const float*)d_in[9];
  const float* img2w = (const float*)d_in[10];
  const float* img2b = (const float*)d_in[11];
  const float* img3w = (const float*)d_in[12];
  const float* img3b = (const float*)d_in[13];
  const float* obs1w = (const float*)d_in[14];
  const float* obs1b = (const float*)d_in[15];
  const float* obs2w = (const float*)d_in[16];
  const float* obs2b = (const float*)d_in[17];
  float* out = (float*)d_out;
  char* ws = (char*)d_ws;

  size_t off = 0;
  auto alloc = [&](size_t bytes) {
    size_t o = off;
    off += (bytes + 255) & ~(size_t)255;
    return o;
  };
  size_t o_flags = alloc(6912 * 4);
  size_t o_embed = alloc(12288ull * 1024 * 2);  // reused as dall (12288x640)
  size_t o_epre = alloc(12288ull * 600 * 2);    // reused (with o_wemb) as h_img
  size_t o_wemb = alloc(1024ull * 600 * 2);
  size_t o_gruwT = alloc(1808ull * 1216 * 2);
  size_t o_o1wT = alloc(608ull * 608 * 2);
  size_t o_o2wT = alloc(64ull * 608 * 2);
  size_t o_w1pT = alloc(640ull * 64 * 2);
  size_t o_i2w = alloc(640ull * 600 * 2);
  size_t o_i3w = alloc(640ull * 64 * 2);
  size_t o_xd = alloc(192ull * XDS * 2);
  size_t o_parts = alloc(192ull * PN * 2);

  unsigned* flags = (unsigned*)(ws + o_flags);
  u16* embed_bf = (u16*)(ws + o_embed);
  u16* dall = (u16*)(ws + o_embed);
  u16* epre = (u16*)(ws + o_epre);
  u16* himg = (u16*)(ws + o_epre);
  u16* wemb = (u16*)(ws + o_wemb);
  u16* gruwT = (u16*)(ws + o_gruwT);
  u16* o1wT = (u16*)(ws + o_o1wT);
  u16* o2wT = (u16*)(ws + o_o2wT);
  u16* w1pT = (u16*)(ws + o_w1pT);
  u16* i2wb = (u16*)(ws + o_i2w);
  u16* i3wb = (u16*)(ws + o_i3w);
  u16* xd = (u16*)(ws + o_xd);
  u16* parts = (u16*)(ws + o_parts);

  auto cgr = [](size_t total) {
    size_t g = (total + 255) / 256;
    return (unsigned)(g > 4096 ? 4096 : g);
  };

  // setup conversions
  conv_pad<<<cgr(12288ull * 1024), 256, 0, stream>>>(embed, embed_bf, 12288, 1024, 12288, 0);
  conv_pad<<<cgr(1024ull * 600), 256, 0, stream>>>(obs1w, wemb, 1024, 600, 1024, 600);
  conv_pad<<<cgr(640ull * 600), 256, 0, stream>>>(img2w, i2wb, 600, 600, 640, 0);
  conv_pad<<<cgr(640ull * 64), 256, 0, stream>>>(img3w, i3wb, 600, 64, 640, 0);
  conv_T<<<cgr(1808ull * 1216), 256, 0, stream>>>(gruw, gruwT, 1200, 1800, 1216, 1808);
  conv_T<<<cgr(608ull * 608), 256, 0, stream>>>(obs1w, o1wT, 600, 600, 608, 608);
  conv_T<<<cgr(64ull * 608), 256, 0, stream>>>(obs2w, o2wT, 600, 64, 608, 64);
  conv_T<<<cgr(640ull * 64), 256, 0, stream>>>(img1w, w1pT, 48, 600, 64, 640);

  k_init<<<192, 256, 0, stream>>>(action, img1w, img1b, xd, flags);

  // epre[t][b][600] = embed @ obs1_w[600:,:] + obs1_b   (bf16, t-major)
  gemm64<4><<<dim3(10, 192), 256, 0, stream>>>(embed_bf, 1024, wemb, 600, obs1b,
                                               epre, 600, 600, 600, 1024);

  // scan: 48 XCD-pinned A-blocks + 12 BD-blocks, 1024 threads each
  ScanArgs sa;
  sa.xd = xd; sa.parts = parts;
  sa.gruwT = gruwT; sa.grub = grub; sa.lns = lns; sa.lnb = lnb;
  sa.dall = dall; sa.out = out;
  sa.o1wT = o1wT; sa.epre = epre;
  sa.o2wT = o2wT; sa.obs2b = obs2b; sa.npo = npo;
  sa.w1pT = w1pT; sa.img1b = img1b; sa.action = action;
  sa.flags = flags;
  scan64<<<60, 1024, 0, stream>>>(sa);

  // batched prior: h_img = elu(deter_all @ img2_w + img2_b), then img3 head
  gemm64<2><<<dim3(10, 192), 256, 0, stream>>>(dall, 640, i2wb, 600, img2b,
                                               himg, 640, 640, 600, 640);
  head_prior<<<192, 256, 0, stream>>>(himg, i3wb, img3b, npr, out);
}